// Round 7
// baseline (68.897 us; speedup 1.0000x reference)
//
#include <hip/hip_runtime.h>
#include <float.h>

// EuclideanCodebook R7: R6 swapped-operand core (A=codebook, B=x, 64 rows/wave,
// 6 MFMA : 2 ds_read) + two overlap fixes:
//  - BROWS=128, 256-thr blocks, grid=512 -> 2 independent blocks/CU
//    (block B's core hides block A's prologue/epilogue; 4-wave barriers).
//  - acc double-buffer (T15): score chunk p AFTER issuing chunk p+1's MFMAs
//    (independent regs -> scheduler interleaves VALU into the matrix shadow).
// e^2 via scoring subtract (esq in LDS, broadcast reads). x^2 dropped.
// dot via f16 split: (2xh)*eh + (2xl)*eh + (2xh)*el, fp32 accumulate.
// ws: [0: esq 4KB | 4096: fragment-ordered codebook image 512KB]

#define Cdim        128
#define KCODES      1024
#define CH          64
#define NCH         16
#define BROWS       128       // 2 row-groups x 64 rows; waves split codes (nt)
#define THREADS     256
#define IMG_OFF     4096
#define CHUNK_BYTES 32768     // [nt0 hi 8K | nt0 lo 8K | nt1 hi 8K | nt1 lo 8K]

typedef _Float16 f16;
typedef __attribute__((ext_vector_type(8)))  _Float16 f16x8;
typedef __attribute__((ext_vector_type(16))) float    f32x16;

// ---------------- e_sq pre-pass (exact fp32) ----------------
__global__ __launch_bounds__(256) void esq_kernel(const float* __restrict__ embed,
                                                  float* __restrict__ esq, int K) {
    int gid  = blockIdx.x * blockDim.x + threadIdx.x;
    int code = gid >> 6;
    int lane = threadIdx.x & 63;
    if (code >= K) return;
    float2 v = ((const float2*)(embed + (size_t)code * Cdim))[lane];
    float  s = fmaf(v.x, v.x, v.y * v.y);
    #pragma unroll
    for (int m = 32; m >= 1; m >>= 1) s += __shfl_xor(s, m, 64);
    if (lane == 0) esq[code] = s;
}

__device__ __forceinline__ void cvt8s(float4 a, float4 b, float scale,
                                      f16x8& h, f16x8& lo) {
    float v[8] = {a.x, a.y, a.z, a.w, b.x, b.y, b.z, b.w};
    #pragma unroll
    for (int i = 0; i < 8; ++i) {
        float s = v[i] * scale;
        f16 hh = (f16)s;
        h[i]  = hh;
        lo[i] = (f16)(s - (float)hh);
    }
}

// ---- codebook -> fragment-order image; one thread per (code, kk, lh) ----
// frag addr: IMG_OFF + ch*32768 + nt*16384 + kk*1024 + lh*512 + lm*16 (lo +8192)
__global__ __launch_bounds__(256) void bconv_kernel(const float* __restrict__ embed,
                                                    char* __restrict__ ws) {
    int t    = blockIdx.x * 256 + threadIdx.x;   // 16384 threads
    int code = t >> 4;
    int slot = t & 15;
    int kk   = slot >> 1;
    int lh   = slot & 1;
    int ch = code >> 6, nt = (code >> 5) & 1, lm = code & 31;
    const float4* p = (const float4*)(embed + (size_t)code * Cdim + kk * 16 + lh * 8);
    f16x8 h, lo;
    cvt8s(p[0], p[1], 1.0f, h, lo);
    size_t base = (size_t)IMG_OFF + (size_t)ch * CHUNK_BYTES + nt * 16384
                + kk * 1024 + lh * 512 + lm * 16;
    *(f16x8*)(ws + base)        = h;
    *(f16x8*)(ws + base + 8192) = lo;
}

// ---------------- async global->LDS 16B ----------------
__device__ __forceinline__ void gll16(const void* g, void* l) {
    __builtin_amdgcn_global_load_lds(
        (const __attribute__((address_space(1))) unsigned int*)g,
        (__attribute__((address_space(3))) unsigned int*)l, 16, 0, 0);
}

__global__ __launch_bounds__(THREADS, 2) void vq_kernel(
    const float* __restrict__ x, const float* __restrict__ embed,
    const char* __restrict__ ws, float* __restrict__ outq,
    float* __restrict__ outi) {

    __shared__ __align__(16) char  Bb[2][CHUNK_BYTES];   // 64KB dbuf
    __shared__ __align__(16) float esq_lds[KCODES];      // 4KB
    __shared__ float mrg_v[2][BROWS];
    __shared__ int   mrg_i[2][BROWS];
    __shared__ int   winners[BROWS];

    const int tid  = threadIdx.x;
    const int wid  = tid >> 6;          // wave 0..3
    const int l    = tid & 63;
    const int lm   = l & 31;
    const int lh   = l >> 5;
    const int wr   = wid & 1;           // row group (64 rows)
    const int nt   = wid >> 1;          // code half of each chunk
    const int row0 = blockIdx.x * BROWS;
    const int loff = lh * 512 + lm * 16;

    // ---- prologue DMA: chunk 0 (8KB/wave) + esq (1KB/wave) ----
    {
        const char* src = ws + IMG_OFF + wid * 8192 + (size_t)l * 16;
        char*       dst = &Bb[0][wid * 8192];
        #pragma unroll
        for (int i = 0; i < 8; ++i) gll16(src + i * 1024, dst + i * 1024);
        gll16(ws + wid * 1024 + (size_t)l * 16, (char*)esq_lds + wid * 1024);
    }

    // ---- x rows -> B-fragments (2*xh, 2*xl), 2 n-tiles of 32 rows ----
    f16x8 bxh[2][8], bxl[2][8];
    #pragma unroll
    for (int n = 0; n < 2; ++n) {
        const float* xr = x + (size_t)(row0 + wr * 64 + n * 32 + lm) * Cdim + lh * 8;
        #pragma unroll
        for (int kk = 0; kk < 8; ++kk) {
            float4 v0 = *(const float4*)(xr + kk * 16);
            float4 v1 = *(const float4*)(xr + kk * 16 + 4);
            cvt8s(v0, v1, 2.0f, bxh[n][kk], bxl[n][kk]);
        }
    }

    float best0 = -FLT_MAX, best1 = -FLT_MAX;
    int   bidx0 = 0,        bidx1 = 0;

    // compute chunk ch into (A0,A1); barriers + prefetch of ch+1 inside
    auto compute = [&](int ch, f32x16& A0, f32x16& A1) {
        const int cur = ch & 1, nxt = cur ^ 1;
        __builtin_amdgcn_s_barrier();            // all done reading Bb[nxt]
        if (ch + 1 < NCH) {
            const char* src = ws + IMG_OFF + (size_t)(ch + 1) * CHUNK_BYTES
                            + wid * 8192 + (size_t)l * 16;
            char* dst = &Bb[nxt][wid * 8192];
            #pragma unroll
            for (int i = 0; i < 8; ++i) gll16(src + i * 1024, dst + i * 1024);
            asm volatile("s_waitcnt vmcnt(8)" ::: "memory");   // chunk ch staged
        } else {
            asm volatile("s_waitcnt vmcnt(0)" ::: "memory");
        }
        __builtin_amdgcn_s_barrier();            // chunk ch visible block-wide

        #pragma unroll
        for (int r = 0; r < 16; ++r) { A0[r] = 0.f; A1[r] = 0.f; }

        const char* bbA = &Bb[cur][nt * 16384 + loff];
        f16x8 aeh = *(const f16x8*)(bbA);
        f16x8 ael = *(const f16x8*)(bbA + 8192);
        __builtin_amdgcn_s_setprio(1);
        #pragma unroll
        for (int kk = 0; kk < 8; ++kk) {
            f16x8 aehN, aelN;
            if (kk < 7) {
                aehN = *(const f16x8*)(bbA + (kk + 1) * 1024);
                aelN = *(const f16x8*)(bbA + 8192 + (kk + 1) * 1024);
            }
            A0 = __builtin_amdgcn_mfma_f32_32x32x16_f16(aeh, bxh[0][kk], A0, 0, 0, 0);
            A1 = __builtin_amdgcn_mfma_f32_32x32x16_f16(aeh, bxh[1][kk], A1, 0, 0, 0);
            A0 = __builtin_amdgcn_mfma_f32_32x32x16_f16(ael, bxh[0][kk], A0, 0, 0, 0);
            A1 = __builtin_amdgcn_mfma_f32_32x32x16_f16(ael, bxh[1][kk], A1, 0, 0, 0);
            A0 = __builtin_amdgcn_mfma_f32_32x32x16_f16(aeh, bxl[0][kk], A0, 0, 0, 0);
            A1 = __builtin_amdgcn_mfma_f32_32x32x16_f16(aeh, bxl[1][kk], A1, 0, 0, 0);
            aeh = aehN; ael = aelN;
        }
        __builtin_amdgcn_s_setprio(0);
    };

    // score chunk ch's accs (s = 2*dot - e^2, codes ascend, strict >)
    auto score = [&](int ch, const f32x16& A0, const f32x16& A1) {
        const int cb = ch * CH + nt * 32 + lh * 4;
        #pragma unroll
        for (int g = 0; g < 4; ++g) {
            float4 e4 = *(const float4*)&esq_lds[cb + g * 8];
            #pragma unroll
            for (int j = 0; j < 4; ++j) {
                const int r = g * 4 + j;
                const int code = cb + g * 8 + j;
                float s0 = A0[r] - ((const float*)&e4)[j];
                float s1 = A1[r] - ((const float*)&e4)[j];
                if (s0 > best0) { best0 = s0; bidx0 = code; }
                if (s1 > best1) { best1 = s1; bidx1 = code; }
            }
        }
    };

    f32x16 aA0, aA1, aB0, aB1;
    compute(0, aA0, aA1);
    #pragma unroll 1
    for (int b = 0; b < 7; ++b) {
        compute(2 * b + 1, aB0, aB1);
        score  (2 * b,     aA0, aA1);      // overlaps chunk 2b+1's MFMA drain
        compute(2 * b + 2, aA0, aA1);
        score  (2 * b + 1, aB0, aB1);
    }
    compute(15, aB0, aB1);
    score  (14, aA0, aA1);
    score  (15, aB0, aB1);

    // ---- merge lh halves (different codes, same rows) ----
    {
        float v; int vi;
        v = __shfl_xor(best0, 32, 64); vi = __shfl_xor(bidx0, 32, 64);
        if (v > best0 || (v == best0 && vi < bidx0)) { best0 = v; bidx0 = vi; }
        v = __shfl_xor(best1, 32, 64); vi = __shfl_xor(bidx1, 32, 64);
        if (v > best1 || (v == best1 && vi < bidx1)) { best1 = v; bidx1 = vi; }
    }
    // ---- wave-pair merge via LDS (code halves nt=0/1) ----
    if (lh == 0) {
        mrg_v[nt][wr * 64 + lm]      = best0;  mrg_i[nt][wr * 64 + lm]      = bidx0;
        mrg_v[nt][wr * 64 + 32 + lm] = best1;  mrg_i[nt][wr * 64 + 32 + lm] = bidx1;
    }
    __syncthreads();
    if (tid < BROWS) {
        float v0 = mrg_v[0][tid]; int i0 = mrg_i[0][tid];
        float v1 = mrg_v[1][tid]; int i1 = mrg_i[1][tid];
        int bi = (v1 > v0 || (v1 == v0 && i1 < i0)) ? i1 : i0;
        winners[tid] = bi;
        outi[row0 + tid] = (float)bi;
    }
    __syncthreads();

    // ---- gather quantized = embed[winner] (exact fp32 copy) ----
    #pragma unroll
    for (int i = 0; i < 16; ++i) {
        int pos = i * THREADS + tid;
        int r = pos >> 5, c4 = pos & 31;
        int idx = winners[r];
        float4 v = ((const float4*)(embed + (size_t)idx * Cdim))[c4];
        ((float4*)(outq + (size_t)(row0 + r) * Cdim))[c4] = v;
    }
}

extern "C" void kernel_launch(void* const* d_in, const int* in_sizes, int n_in,
                              void* d_out, int out_size, void* d_ws, size_t ws_size,
                              hipStream_t stream) {
    const float* x     = (const float*)d_in[0];
    const float* embed = (const float*)d_in[1];
    const int M = in_sizes[0] / Cdim;   // 65536
    const int K = in_sizes[1] / Cdim;   // 1024
    float* outq = (float*)d_out;
    float* outi = outq + (size_t)M * Cdim;

    esq_kernel <<<K / 4, 256, 0, stream>>>(embed, (float*)d_ws, K);
    bconv_kernel<<<64, 256, 0, stream>>>(embed, (char*)d_ws);
    vq_kernel  <<<M / BROWS, THREADS, 0, stream>>>(x, embed, (const char*)d_ws,
                                                   outq, outi);
}